// Round 12
// baseline (290.527 us; speedup 1.0000x reference)
//
#include <hip/hip_runtime.h>

typedef float floatx16 __attribute__((ext_vector_type(16)));
typedef __bf16 bf16x8 __attribute__((ext_vector_type(8)));
using u16 = unsigned short;
using u32 = unsigned int;

#define GLOBAL_AS __attribute__((address_space(1)))
#define LDS_AS    __attribute__((address_space(3)))

__device__ __forceinline__ u32 rne_bf16(float f) {
  u32 u = __float_as_uint(f);
  return (u + 0x7FFFu + ((u >> 16) & 1u)) >> 16;  // RNE
}

// ---------------- A: fp32 -> bf16, tile-permuted for 32x32x16 frags ----------------
// (R10: coalesced reads -> LDS permute -> linear 32KB writes)
__global__ __launch_bounds__(256) void cvt_x_perm(const float* __restrict__ x,
                                                  u16* __restrict__ xb, int K) {
  __shared__ u16 sm[16384];
  const int tid = threadIdx.x;
  const int Kt = K >> 6;
  const int pn = blockIdx.x / Kt, tt = blockIdx.x % Kt;
  const float* src = x + (size_t)pn * 256 * K + tt * 64;
#pragma unroll
  for (int j = 0; j < 16; ++j) {
    const int fc = j * 256 + tid;
    const int row = fc >> 4, kl4 = fc & 15;
    const float4 v = *(const float4*)(src + (size_t)row * K + kl4 * 4);
    uint2 o;
    o.x = rne_bf16(v.x) | (rne_bf16(v.y) << 16);
    o.y = rne_bf16(v.z) | (rne_bf16(v.w) << 16);
    const int gi = row >> 5, rowin = row & 31;
    const int ks = kl4 >> 2;
    const int lane = rowin + 32 * ((kl4 >> 1) & 1);
    const int e4 = (kl4 & 1) * 4;
    *(uint2*)(sm + gi * 2048 + ks * 512 + lane * 8 + e4) = o;
  }
  __syncthreads();
  u16* dst = xb + (size_t)pn * 256 * K + (size_t)tt * 16384;
#pragma unroll
  for (int j = 0; j < 8; ++j) {
    const int o = (j * 256 + tid) * 8;
    *(uint4*)(dst + o) = *(const uint4*)(sm + o);
  }
}

// ---------------- B: fp32 -> ternary bf16, same tile-permuted layout ----------------
__global__ __launch_bounds__(256) void quant_w_perm(const float* __restrict__ w,
                                                    u16* __restrict__ wb, int K) {
  __shared__ u16 sm[16384];
  const int tid = threadIdx.x;
  const int Kt = K >> 6;
  const int pn = blockIdx.x / Kt, tt = blockIdx.x % Kt;
  const float* src = w + (size_t)pn * 256 * K + tt * 64;
#pragma unroll
  for (int j = 0; j < 16; ++j) {
    const int fc = j * 256 + tid;
    const int row = fc >> 4, kl4 = fc & 15;
    const float4 v = *(const float4*)(src + (size_t)row * K + kl4 * 4);
    float vv[4] = {v.x, v.y, v.z, v.w};
    u32 r[4];
#pragma unroll
    for (int e = 0; e < 4; ++e)
      r[e] = (vv[e] > 0.05f) ? 0x3F80u : ((vv[e] < -0.05f) ? 0xBF80u : 0u);
    uint2 o;
    o.x = r[0] | (r[1] << 16);
    o.y = r[2] | (r[3] << 16);
    const int gi = row >> 5, rowin = row & 31;
    const int ks = kl4 >> 2;
    const int lane = rowin + 32 * ((kl4 >> 1) & 1);
    const int e4 = (kl4 & 1) * 4;
    *(uint2*)(sm + gi * 2048 + ks * 512 + lane * 8 + e4) = o;
  }
  __syncthreads();
  u16* dst = wb + (size_t)pn * 256 * K + (size_t)tt * 16384;
#pragma unroll
  for (int j = 0; j < 8; ++j) {
    const int o = (j * 256 + tid) * 8;
    *(uint4*)(dst + o) = *(const uint4*)(sm + o);
  }
}

// ---------------- 256x256 BK=64 GEMM, mfma 32x32x16, single-barrier tiles ----------------
// Layout/MFMA/epilogue = R11. New sync structure:
//   - ALL 8 stage-gloads for tile t+1 issued at TOP of tile t, into bufo ONLY
//     -> no in-tile WAR -> NO block barriers inside the tile.
//   - Per-wave counted lgkm pipeline: issue {af01,bflo}(12)+{bfhi}(4);
//     lgkm(4)->Q0(m01,n0); issue {af23->af2}(8); lgkm(8)->Q1(m01,n1);
//     lgkm(0)->Q2(m23,n0),Q3(m23,n1).  (DS returns in-order -> counts exact.)
//   - Tile end: vmcnt(0) (stages led by a full tile ~2400cyc -> free) + ONE
//     barrier (publish: every chunk is staged by all 8 waves, so barrier after
//     per-wave vmcnt(0) is the exact point bufo is globally complete; also WAR:
//     all reads of bufc drained via lgkm(0) before each wave's barrier arrival).
__global__ __launch_bounds__(512, 2) void gemm_bin_flow(
    const u16* __restrict__ Ap, const u16* __restrict__ Bp,
    const float* __restrict__ bias, float* __restrict__ C,
    int M, int N, int K) {
  __shared__ u16 lds[65536];  // 2 buf x (A 16384 | B 16384) u16

  const int tid = threadIdx.x;
  const int w = tid >> 6, l = tid & 63;
  const int wr = w >> 2, wc = w & 3;

  const int nbn = N >> 8;
  int wg = blockIdx.x;
  const int nwg = gridDim.x;
  if ((nwg & 7) == 0) wg = (wg & 7) * (nwg >> 3) + (wg >> 3);  // XCD swizzle (bijective)
  const int bm = wg / nbn, bn = wg % nbn;

  const int T = K >> 6;

  const u16* const Abase = Ap + (size_t)bm * ((size_t)K << 8) + tid * 8;
  const u16* const Bbase = Bp + (size_t)bn * ((size_t)K << 8) + tid * 8;

  const u16* const afp0 = lds + wr * 8192 + l * 8;
  const u16* const bfp0 = lds + 16384 + wc * 4096 + l * 8;

  floatx16 acc[4][2] = {};
  bf16x8 af[8], af2[8], bflo[4], bfhi[4];

#define GLOAD(gptr, u16off)                                                    \
  __builtin_amdgcn_global_load_lds((const GLOBAL_AS void*)(gptr),              \
                                   (LDS_AS void*)(lds + (u16off)), 16, 0, 0)
#define STAGE8(tt, bufdst)                                                     \
  {                                                                            \
    const size_t tb_ = (size_t)(tt) * 16384;                                   \
    GLOAD(Abase + tb_ + 0 * 4096, (bufdst) + 0 + tid * 8);                     \
    GLOAD(Abase + tb_ + 1 * 4096, (bufdst) + 4096 + tid * 8);                  \
    GLOAD(Abase + tb_ + 2 * 4096, (bufdst) + 8192 + tid * 8);                  \
    GLOAD(Abase + tb_ + 3 * 4096, (bufdst) + 12288 + tid * 8);                 \
    GLOAD(Bbase + tb_ + 0 * 4096, (bufdst) + 16384 + tid * 8);                 \
    GLOAD(Bbase + tb_ + 1 * 4096, (bufdst) + 20480 + tid * 8);                 \
    GLOAD(Bbase + tb_ + 2 * 4096, (bufdst) + 24576 + tid * 8);                 \
    GLOAD(Bbase + tb_ + 3 * 4096, (bufdst) + 28672 + tid * 8);                 \
  }

  // prologue: stage tile 0 -> buf0, drain, publish
  STAGE8(0, 0)
  asm volatile("s_waitcnt vmcnt(0)" ::: "memory");
  __builtin_amdgcn_s_barrier();

  for (int t = 0; t < T; ++t) {
    const int bufc = (t & 1) << 15;
    const int bufo = bufc ^ 32768;
    const bool st1 = (t + 1 < T);

    if (st1) STAGE8(t + 1, bufo)

    const u16* afp = afp0 + bufc;
    const u16* bfp = bfp0 + bufc;

    // group 1: af m0,m1 (8) + bflo (4); group 2: bfhi (4)
#pragma unroll
    for (int m = 0; m < 2; ++m)
#pragma unroll
      for (int ks = 0; ks < 4; ++ks)
        af[m * 4 + ks] = *(const bf16x8*)(afp + m * 2048 + ks * 512);
#pragma unroll
    for (int ks = 0; ks < 4; ++ks) bflo[ks] = *(const bf16x8*)(bfp + ks * 512);
#pragma unroll
    for (int ks = 0; ks < 4; ++ks) bfhi[ks] = *(const bf16x8*)(bfp + 2048 + ks * 512);

    asm volatile("s_waitcnt lgkmcnt(4)" ::: "memory");  // af01+bflo landed (bfhi outstanding)
    __builtin_amdgcn_sched_barrier(0);
    __builtin_amdgcn_s_setprio(1);
#pragma unroll
    for (int ks = 0; ks < 4; ++ks)
#pragma unroll
      for (int m = 0; m < 2; ++m)
        acc[m][0] = __builtin_amdgcn_mfma_f32_32x32x16_bf16(
            af[m * 4 + ks], bflo[ks], acc[m][0], 0, 0, 0);
    __builtin_amdgcn_s_setprio(0);

    // group 3: af m2,m3 -> af2 (8), issued under Q0/Q1
#pragma unroll
    for (int m = 0; m < 2; ++m)
#pragma unroll
      for (int ks = 0; ks < 4; ++ks)
        af2[m * 4 + ks] = *(const bf16x8*)(afp + 4096 + m * 2048 + ks * 512);

    asm volatile("s_waitcnt lgkmcnt(8)" ::: "memory");  // bfhi landed (af2 outstanding)
    __builtin_amdgcn_sched_barrier(0);
    __builtin_amdgcn_s_setprio(1);
#pragma unroll
    for (int ks = 0; ks < 4; ++ks)
#pragma unroll
      for (int m = 0; m < 2; ++m)
        acc[m][1] = __builtin_amdgcn_mfma_f32_32x32x16_bf16(
            af[m * 4 + ks], bfhi[ks], acc[m][1], 0, 0, 0);
    __builtin_amdgcn_s_setprio(0);

    asm volatile("s_waitcnt lgkmcnt(0)" ::: "memory");  // af2 landed
    __builtin_amdgcn_sched_barrier(0);
    __builtin_amdgcn_s_setprio(1);
#pragma unroll
    for (int ks = 0; ks < 4; ++ks)
#pragma unroll
      for (int m = 0; m < 2; ++m)
        acc[2 + m][0] = __builtin_amdgcn_mfma_f32_32x32x16_bf16(
            af2[m * 4 + ks], bflo[ks], acc[2 + m][0], 0, 0, 0);
#pragma unroll
    for (int ks = 0; ks < 4; ++ks)
#pragma unroll
      for (int m = 0; m < 2; ++m)
        acc[2 + m][1] = __builtin_amdgcn_mfma_f32_32x32x16_bf16(
            af2[m * 4 + ks], bfhi[ks], acc[2 + m][1], 0, 0, 0);
    __builtin_amdgcn_s_setprio(0);

    if (st1) {
      asm volatile("s_waitcnt vmcnt(0)" ::: "memory");  // tile t+1 landed (1-tile lead)
      __builtin_amdgcn_s_barrier();                      // publish bufo / retire bufc
    }
  }
#undef STAGE8
#undef GLOAD

  // ---- epilogue: C/D col=l&31, row=(q&3)+8*(q>>2)+4*(l>>5) (m74/m101-verified) ----
  const int colq = l & 31;
  const int hi4 = (l >> 5) * 4;
#pragma unroll
  for (int m = 0; m < 4; ++m) {
    const int rowb = bm * 256 + wr * 128 + m * 32 + hi4;
#pragma unroll
    for (int n = 0; n < 2; ++n) {
      const int col = bn * 256 + wc * 64 + n * 32 + colq;
      const float bv = bias[col];
      float* cp = C + (size_t)rowb * N + col;
#pragma unroll
      for (int q = 0; q < 16; ++q) {
        const int dr = (q & 3) + 8 * (q >> 2);
        cp[(size_t)dr * N] = acc[m][n][q] + bv;
      }
    }
  }
}

// ---------------- fallback: slow but correct ----------------
__global__ void gemm_naive_kernel(const float* __restrict__ x, const float* __restrict__ wgt,
                                  const float* __restrict__ bias, float* __restrict__ out,
                                  int M, int N, int K) {
  long long idx = (long long)blockIdx.x * blockDim.x + threadIdx.x;
  if (idx >= (long long)M * N) return;
  int o = (int)(idx % N);
  int m = (int)(idx / N);
  const float* xr = x + (size_t)m * K;
  const float* wr = wgt + (size_t)o * K;
  float s = 0.f;
  for (int i = 0; i < K; ++i) {
    float wv = wr[i];
    float t = (wv > 0.05f) ? 1.f : ((wv < -0.05f) ? -1.f : 0.f);
    s = fmaf(xr[i], t, s);
  }
  out[idx] = s + bias[o];
}

extern "C" void kernel_launch(void* const* d_in, const int* in_sizes, int n_in,
                              void* d_out, int out_size, void* d_ws, size_t ws_size,
                              hipStream_t stream) {
  const float* x    = (const float*)d_in[0];
  const float* wgt  = (const float*)d_in[1];
  const float* bias = (const float*)d_in[2];
  float* out = (float*)d_out;

  const int N = in_sizes[2];                 // out features
  const int K = in_sizes[1] / N;             // in features
  const int M = in_sizes[0] / K;             // batch rows

  const size_t need = ((size_t)M * K + (size_t)N * K) * sizeof(u16);
  if (ws_size >= need && (M % 256 == 0) && (N % 256 == 0) && (K % 64 == 0) && K >= 192) {
    u16* xb = (u16*)d_ws;
    u16* wb = xb + (size_t)M * K;
    const int Kt = K / 64;
    cvt_x_perm<<<(M / 256) * Kt, 256, 0, stream>>>(x, xb, K);
    quant_w_perm<<<(N / 256) * Kt, 256, 0, stream>>>(wgt, wb, K);
    const int grid = (M / 256) * (N / 256);
    gemm_bin_flow<<<grid, 512, 0, stream>>>(xb, wb, bias, out, M, N, K);
  } else {
    const long long total = (long long)M * N;
    gemm_naive_kernel<<<(unsigned)((total + 255) / 256), 256, 0, stream>>>(x, wgt, bias, out, M, N, K);
  }
}